// Round 4
// baseline (148.364 us; speedup 1.0000x reference)
//
#include <hip/hip_runtime.h>

// segment_sum via fixed-stride bucketing + gather, exact overflow path.
// E = 1M edges, D = 64 f32 features, N = 100K nodes, ws ~1GB.
//
// Phase 1: memset cursor[N]+ovf_cnt = 0                      (400 KB)
// Phase 2: scatter  pos = atomicAdd(cursor[t]); pos<32 ? bucket : ovf list
// Phase 3: gather   16-lane group per node, NT float4 loads, 4-deep unroll
// Phase 4: cleanup  atomicAdd overflow edges (expected count: 0)
//
// ws ints: cursor[N] | ovf_cnt | ovf[2*OVF_CAP] | bucket[N*CAP]

typedef float f4 __attribute__((ext_vector_type(4)));

#define FEAT 64
#define CAP 32            // one 128B line per node row (avg deg 10)
#define OVF_CAP (1 << 20)

__global__ void __launch_bounds__(256)
scatter_kernel(const int* __restrict__ tgt, int* __restrict__ cursor,
               int* __restrict__ bucket, int* __restrict__ ovf_cnt,
               int* __restrict__ ovf, int E) {
    int i = blockIdx.x * 256 + threadIdx.x;
    if (i >= E) return;
    int t = tgt[i];
    int pos = atomicAdd(&cursor[t], 1);
    if (pos < CAP) {
        __builtin_nontemporal_store(i, &bucket[t * CAP + pos]);
    } else {                          // exact fallback, expected never
        int q = atomicAdd(ovf_cnt, 1);
        if (q < OVF_CAP) { ovf[2 * q] = t; ovf[2 * q + 1] = i; }
    }
}

// 16-lane group per node; lane = float4 slot; 4 rows in flight per group
__global__ void __launch_bounds__(256)
gather_kernel(const f4* __restrict__ mj4, const int* __restrict__ cursor,
              const int* __restrict__ bucket, f4* __restrict__ out4, int N) {
    int gid = (blockIdx.x * 256 + threadIdx.x) >> 4;
    int l = threadIdx.x & 15;
    if (gid >= N) return;
    int deg = cursor[gid];
    if (deg > CAP) deg = CAP;
    const int* row = bucket + gid * CAP;   // exactly one 128B line
    f4 acc = {0.f, 0.f, 0.f, 0.f};
    int j = 0;
    for (; j + 3 < deg; j += 4) {
        int e0 = row[j], e1 = row[j + 1], e2 = row[j + 2], e3 = row[j + 3];
        f4 a = __builtin_nontemporal_load(&mj4[(size_t)e0 * 16 + l]);
        f4 b = __builtin_nontemporal_load(&mj4[(size_t)e1 * 16 + l]);
        f4 c = __builtin_nontemporal_load(&mj4[(size_t)e2 * 16 + l]);
        f4 d = __builtin_nontemporal_load(&mj4[(size_t)e3 * 16 + l]);
        acc += a + b + c + d;
    }
    for (; j < deg; ++j) {
        acc += __builtin_nontemporal_load(&mj4[(size_t)row[j] * 16 + l]);
    }
    __builtin_nontemporal_store(acc, &out4[(size_t)gid * 16 + l]);
}

// expected n == 0; exact correction for any degree distribution
__global__ void __launch_bounds__(256)
cleanup_kernel(const float* __restrict__ mj, const int* __restrict__ ovf_cnt,
               const int* __restrict__ ovf, float* __restrict__ out) {
    int n = *ovf_cnt;
    if (n > OVF_CAP) n = OVF_CAP;
    int sub = threadIdx.x >> 6;   // 4 entries in parallel
    int lane = threadIdx.x & 63;
    for (int k = sub; k < n; k += 4) {
        int t = ovf[2 * k], e = ovf[2 * k + 1];
        atomicAdd(&out[(size_t)t * FEAT + lane], mj[(size_t)e * FEAT + lane]);
    }
}

extern "C" void kernel_launch(void* const* d_in, const int* in_sizes, int n_in,
                              void* d_out, int out_size, void* d_ws, size_t ws_size,
                              hipStream_t stream) {
    const float* mj = (const float*)d_in[0];
    const int* edge_index = (const int*)d_in[1];  // [2, E] int32 row-major
    int E = in_sizes[1] / 2;
    const int* tgt = edge_index + E;              // row 1 = targets
    int N = out_size / FEAT;                      // 100,000

    int* cursor  = (int*)d_ws;                    // N
    int* ovf_cnt = cursor + N;                    // 1
    int* ovf     = ovf_cnt + 1;                   // 2*OVF_CAP
    int* bucket  = ovf + 2 * OVF_CAP;             // N*CAP (12.8 MB)

    hipMemsetAsync(cursor, 0, (size_t)(N + 1) * sizeof(int), stream);

    int eblk = (E + 255) / 256;
    scatter_kernel<<<eblk, 256, 0, stream>>>(tgt, cursor, bucket, ovf_cnt, ovf, E);

    int gblk = (N * 16 + 255) / 256;
    gather_kernel<<<gblk, 256, 0, stream>>>(
        (const f4*)mj, cursor, bucket, (f4*)d_out, N);

    cleanup_kernel<<<1, 256, 0, stream>>>(mj, ovf_cnt, ovf, (float*)d_out);
}

// Round 5
// 127.230 us; speedup vs baseline: 1.1661x; 1.1661x over previous
//
#include <hip/hip_runtime.h>

// segment_sum via fixed-stride bucketing + gather, exact overflow path.
// E = 1M edges, D = 64 f32 features, N = 100K nodes, ws ~1GB.
// R4: identical to R3 but with ALL nontemporal hints removed (R3 regressed
// 123->148 us; NT store on scatter's random 4B writes suspected of bypassing
// L2 write-coalescing).
//
// ws ints: cursor[N] | ovf_cnt | ovf[2*OVF_CAP] | bucket[N*CAP]

typedef float f4 __attribute__((ext_vector_type(4)));

#define FEAT 64
#define CAP 32            // one 128B line per node row (avg deg 10)
#define OVF_CAP (1 << 20)

__global__ void __launch_bounds__(256)
scatter_kernel(const int* __restrict__ tgt, int* __restrict__ cursor,
               int* __restrict__ bucket, int* __restrict__ ovf_cnt,
               int* __restrict__ ovf, int E) {
    int i = blockIdx.x * 256 + threadIdx.x;
    if (i >= E) return;
    int t = tgt[i];
    int pos = atomicAdd(&cursor[t], 1);
    if (pos < CAP) {
        bucket[t * CAP + pos] = i;    // plain store: L2 coalesces the region
    } else {                          // exact fallback, expected never
        int q = atomicAdd(ovf_cnt, 1);
        if (q < OVF_CAP) { ovf[2 * q] = t; ovf[2 * q + 1] = i; }
    }
}

// 16-lane group per node; lane = float4 slot; 4 rows in flight per group
__global__ void __launch_bounds__(256)
gather_kernel(const f4* __restrict__ mj4, const int* __restrict__ cursor,
              const int* __restrict__ bucket, f4* __restrict__ out4, int N) {
    int gid = (blockIdx.x * 256 + threadIdx.x) >> 4;
    int l = threadIdx.x & 15;
    if (gid >= N) return;
    int deg = cursor[gid];
    if (deg > CAP) deg = CAP;
    const int* row = bucket + gid * CAP;   // exactly one 128B line
    f4 acc = {0.f, 0.f, 0.f, 0.f};
    int j = 0;
    for (; j + 3 < deg; j += 4) {
        int e0 = row[j], e1 = row[j + 1], e2 = row[j + 2], e3 = row[j + 3];
        f4 a = mj4[(size_t)e0 * 16 + l];
        f4 b = mj4[(size_t)e1 * 16 + l];
        f4 c = mj4[(size_t)e2 * 16 + l];
        f4 d = mj4[(size_t)e3 * 16 + l];
        acc += a + b + c + d;
    }
    for (; j < deg; ++j) {
        acc += mj4[(size_t)row[j] * 16 + l];
    }
    out4[(size_t)gid * 16 + l] = acc;
}

// expected n == 0; exact correction for any degree distribution
__global__ void __launch_bounds__(256)
cleanup_kernel(const float* __restrict__ mj, const int* __restrict__ ovf_cnt,
               const int* __restrict__ ovf, float* __restrict__ out) {
    int n = *ovf_cnt;
    if (n > OVF_CAP) n = OVF_CAP;
    int sub = threadIdx.x >> 6;   // 4 entries in parallel
    int lane = threadIdx.x & 63;
    for (int k = sub; k < n; k += 4) {
        int t = ovf[2 * k], e = ovf[2 * k + 1];
        atomicAdd(&out[(size_t)t * FEAT + lane], mj[(size_t)e * FEAT + lane]);
    }
}

extern "C" void kernel_launch(void* const* d_in, const int* in_sizes, int n_in,
                              void* d_out, int out_size, void* d_ws, size_t ws_size,
                              hipStream_t stream) {
    const float* mj = (const float*)d_in[0];
    const int* edge_index = (const int*)d_in[1];  // [2, E] int32 row-major
    int E = in_sizes[1] / 2;
    const int* tgt = edge_index + E;              // row 1 = targets
    int N = out_size / FEAT;                      // 100,000

    int* cursor  = (int*)d_ws;                    // N
    int* ovf_cnt = cursor + N;                    // 1
    int* ovf     = ovf_cnt + 1;                   // 2*OVF_CAP
    int* bucket  = ovf + 2 * OVF_CAP;             // N*CAP (12.8 MB)

    hipMemsetAsync(cursor, 0, (size_t)(N + 1) * sizeof(int), stream);

    int eblk = (E + 255) / 256;
    scatter_kernel<<<eblk, 256, 0, stream>>>(tgt, cursor, bucket, ovf_cnt, ovf, E);

    int gblk = (N * 16 + 255) / 256;
    gather_kernel<<<gblk, 256, 0, stream>>>(
        (const f4*)mj, cursor, bucket, (f4*)d_out, N);

    cleanup_kernel<<<1, 256, 0, stream>>>(mj, ovf_cnt, ovf, (float*)d_out);
}